// Round 1
// 486.269 us; speedup vs baseline: 1.0983x; 1.0983x over previous
//
#include <hip/hip_runtime.h>

typedef short bf16x8 __attribute__((ext_vector_type(8)));
typedef float f32x4 __attribute__((ext_vector_type(4)));

__device__ inline unsigned short f2bf(float f) {
    union { float f; unsigned u; } v; v.f = f;
    unsigned u = v.u;
    u += 0x7fffu + ((u >> 16) & 1u);   // RNE
    return (unsigned short)(u >> 16);
}

#define KPAD 264   // 256 + 8 bf16 pad -> 2-way bank aliasing only (free)

// Swizzle W (fp32 [256][256] row-major) -> bf16 MFMA A-fragment order:
// wsw[((mt*8+ks)*64 + lane)*8 + jj] = W[mt*16 + (lane&15)][ks*32 + (lane>>4)*8 + jj]
__global__ void prep_weights(const float* __restrict__ wl,
                             const float* __restrict__ wr,
                             const float* __restrict__ wo,
                             unsigned short* __restrict__ wsw) {
    int idx = blockIdx.x * 256 + threadIdx.x;   // 0 .. 196607
    int w    = idx >> 16;
    int e    = idx & 65535;
    int jj   = e & 7;
    int lane = (e >> 3) & 63;
    int kmt  = e >> 9;          // mt*8 + ks
    int ks   = kmt & 7;
    int mt   = kmt >> 3;
    int row = mt * 16 + (lane & 15);
    int col = ks * 32 + (lane >> 4) * 8 + jj;
    const float* src = (w == 0) ? wl : (w == 1) ? wr : wo;
    wsw[idx] = f2bf(src[row * 256 + col]);
}

// One block = 16 tokens. 512 threads = 8 waves; each wave owns 2 M-tiles (32 rows).
// __launch_bounds__(512,4): cap arch regs (VGPR+AGPR) at 128/wave so TWO 8-wave
// blocks co-reside per CU (round-1 showed 1 block/CU = latency-serialized HBM).
__global__ __launch_bounds__(512, 4) void fused_kernel(
    const float* __restrict__ xl_g, const float* __restrict__ xr_g,
    const unsigned short* __restrict__ wsw, float* __restrict__ out) {

    // LDS: stage1 B-tiles XB_l [48][KPAD] @0, XB_r @12672 (bf16, k-contiguous).
    // After barrier, P [144][KPAD] bf16 overlays everything @0 (76032 B).
    // After stage-2 k-loops, P is dead and the same LDS is re-used as the
    // epilogue transpose scratch: 8 waves x 9472 B (= 16 tok x 148 f32).
    __shared__ __align__(16) unsigned short lds[38016];

    const int tid  = threadIdx.x;
    const int blk  = blockIdx.x;
    const int wave = tid >> 6;
    const int lane = tid & 63;
    const int q    = lane >> 4;
    const int l15  = lane & 15;

    // ---- Stage 0: global -> LDS staging, fp32 -> bf16, c = i*16 + t layout ----
    const float* srcs[2] = { xl_g + (size_t)blk * 12288, xr_g + (size_t)blk * 12288 };
    for (int a = 0; a < 2; ++a) {
        const float4* s4 = (const float4*)srcs[a];
        unsigned short* dst = lds + a * 12672;
        #pragma unroll
        for (int it = 0; it < 6; ++it) {
            int g4 = it * 512 + tid;        // 0..3071, coalesced 16B
            float4 v = s4[g4];
            int g = g4 * 4;                  // 768 % 4 == 0: never straddles a token
            int tok = g / 768;
            int m0 = g - tok * 768;
            float vv[4] = {v.x, v.y, v.z, v.w};
            #pragma unroll
            for (int e = 0; e < 4; ++e) {
                int mm = m0 + e;
                int I = mm / 3;
                int i = mm - I * 3;
                dst[(i * 16 + tok) * KPAD + I] = f2bf(vv[e]);
            }
        }
    }
    __syncthreads();

    // ---- Stage 1: xl = W_l * x_l, xr = W_r * x_r  (two M-tiles per wave) ----
    const bf16x8* wlf = (const bf16x8*)(wsw);
    const bf16x8* wrf = (const bf16x8*)(wsw + 65536);
    const bf16x8* wof = (const bf16x8*)(wsw + 131072);

    f32x4 accL[2][3] = {};
    f32x4 accR[2][3] = {};

    #pragma unroll
    for (int k = 0; k < 8; ++k) {
        const int koff = k * 32 + q * 8;
        bf16x8 bl[3], br[3];
        #pragma unroll
        for (int nt = 0; nt < 3; ++nt) {
            bl[nt] = *(const bf16x8*)&lds[(nt * 16 + l15) * KPAD + koff];
            br[nt] = *(const bf16x8*)&lds[12672 + (nt * 16 + l15) * KPAD + koff];
        }
        #pragma unroll
        for (int m = 0; m < 2; ++m) {
            const int mt = wave * 2 + m;
            bf16x8 al = wlf[(mt * 8 + k) * 64 + lane];
            bf16x8 ar = wrf[(mt * 8 + k) * 64 + lane];
            #pragma unroll
            for (int nt = 0; nt < 3; ++nt) {
                accL[m][nt] = __builtin_amdgcn_mfma_f32_16x16x32_bf16(al, bl[nt], accL[m][nt], 0, 0, 0);
                accR[m][nt] = __builtin_amdgcn_mfma_f32_16x16x32_bf16(ar, br[nt], accR[m][nt], 0, 0, 0);
            }
        }
    }
    __syncthreads();   // all stage-1 LDS reads done; P may overlay XB

    // ---- P build: in-register outer product, write bf16 P[c=(i*3+j)*16+t][r] ----
    #pragma unroll
    for (int m = 0; m < 2; ++m) {
        const int mt = wave * 2 + m;
        const int r0 = mt * 16 + q * 4;      // this lane's 4 consecutive r
        #pragma unroll
        for (int i = 0; i < 3; ++i) {
            #pragma unroll
            for (int j = 0; j < 3; ++j) {
                const int c = (i * 3 + j) * 16 + l15;
                unsigned short h[4];
                #pragma unroll
                for (int reg = 0; reg < 4; ++reg)
                    h[reg] = f2bf(accL[m][i][reg] * accR[m][j][reg]);
                uint2 pk;
                pk.x = (unsigned)h[0] | ((unsigned)h[1] << 16);
                pk.y = (unsigned)h[2] | ((unsigned)h[3] << 16);
                *(uint2*)&lds[c * KPAD + r0] = pk;   // 8B aligned
            }
        }
    }
    __syncthreads();

    // ---- Stage 2: out = W_o * P (256 x 256 x 144) ----
    // Two k-passes (p=0..4, then p=5..8) bound live pf/acc pressure, but BOTH
    // accumulator sets are kept in registers (accA 40 + accB 32 = 72 regs,
    // peak liveness ~104 < 128 cap) so the store epilogue can run once, fully
    // coalesced, instead of the old 4B-per-lane scatter (64 lines/store instr).
    f32x4 accA[2][5] = {};
    f32x4 accB[2][4] = {};
    #pragma unroll
    for (int k = 0; k < 8; ++k) {
        const int koff = k * 32 + q * 8;
        bf16x8 pf[5];
        #pragma unroll
        for (int p = 0; p < 5; ++p)
            pf[p] = *(const bf16x8*)&lds[(p * 16 + l15) * KPAD + koff];
        #pragma unroll
        for (int m = 0; m < 2; ++m) {
            const int mt = wave * 2 + m;
            bf16x8 ao = wof[(mt * 8 + k) * 64 + lane];
            #pragma unroll
            for (int p = 0; p < 5; ++p)
                accA[m][p] = __builtin_amdgcn_mfma_f32_16x16x32_bf16(ao, pf[p], accA[m][p], 0, 0, 0);
        }
    }
    #pragma unroll
    for (int k = 0; k < 8; ++k) {
        const int koff = k * 32 + q * 8;
        bf16x8 pf[4];
        #pragma unroll
        for (int p = 0; p < 4; ++p)
            pf[p] = *(const bf16x8*)&lds[((5 + p) * 16 + l15) * KPAD + koff];
        #pragma unroll
        for (int m = 0; m < 2; ++m) {
            const int mt = wave * 2 + m;
            bf16x8 ao = wof[(mt * 8 + k) * 64 + lane];
            #pragma unroll
            for (int p = 0; p < 4; ++p)
                accB[m][p] = __builtin_amdgcn_mfma_f32_16x16x32_bf16(ao, pf[p], accB[m][p], 0, 0, 0);
        }
    }
    __syncthreads();   // all P reads done; scratch may overlay P

    // ---- Epilogue: per-wave LDS transpose -> fully coalesced float4 stores ----
    // Fragment lane (t=l15, o=q*4+reg) scatters f32 into a per-wave scratch row
    // [16 tok][148 f32] (stride 148 -> 592 B, 16B-aligned rows), then the wave
    // re-reads with tok=lane>>2, sub=lane&3: each float4 store instruction
    // covers 16 tokens x 64B contiguous = 16 FULL cache lines (no RMW).
    float* sf = (float*)(lds + wave * 4736);   // 9472 B per wave, 16B aligned
    const int tok = lane >> 2, sub = lane & 3;
    #pragma unroll
    for (int m = 0; m < 2; ++m) {
        const int mt = wave * 2 + m;
        #pragma unroll
        for (int reg = 0; reg < 4; ++reg) {
            const int o9 = (q * 4 + reg) * 9;
            #pragma unroll
            for (int p = 0; p < 9; ++p) {
                float v = (p < 5) ? accA[m][p][reg] : accB[m][p - 5][reg];
                sf[l15 * 148 + o9 + p] = v;
            }
        }
        __syncthreads();   // scratch visible (also fences the m=1 overwrite)
        float* wdst = out + ((size_t)blk * 16 + tok) * 2304 + mt * 144;
        #pragma unroll
        for (int it = 0; it < 9; ++it) {
            const int f4 = sub + 4 * it;
            float4 v = *(const float4*)&sf[tok * 148 + f4 * 4];
            ((float4*)wdst)[f4] = v;
        }
        __syncthreads();   // reads done before next m overwrites scratch
    }
}

extern "C" void kernel_launch(void* const* d_in, const int* in_sizes, int n_in,
                              void* d_out, int out_size, void* d_ws, size_t ws_size,
                              hipStream_t stream) {
    const float* xl = (const float*)d_in[0];
    const float* xr = (const float*)d_in[1];
    const float* wl = (const float*)d_in[2];
    const float* wr = (const float*)d_in[3];
    const float* wo = (const float*)d_in[4];
    float* out = (float*)d_out;
    unsigned short* wsw = (unsigned short*)d_ws;   // 384 KB bf16 swizzled weights

    prep_weights<<<768, 256, 0, stream>>>(wl, wr, wo, wsw);
    fused_kernel<<<2048, 512, 0, stream>>>(xl, xr, wsw, out);
}